// Round 3
// baseline (252.294 us; speedup 1.0000x reference)
//
#include <hip/hip_runtime.h>

typedef unsigned short u16;
typedef __attribute__((ext_vector_type(8))) _Float16 f16x8;
typedef __attribute__((ext_vector_type(2))) _Float16 f16x2;
typedef __attribute__((ext_vector_type(4))) float f32x4;

#define DEV static __device__ __forceinline__

DEV float bf2f(u16 h){ unsigned u = ((unsigned)h) << 16; return __builtin_bit_cast(float, u); }
DEV u16 f2bf(float f){ unsigned u = __builtin_bit_cast(unsigned, f); u += 0x7FFFu + ((u >> 16) & 1u); return (u16)(u >> 16); }
DEV u16 f2h(float f){ _Float16 h = (_Float16)f; return __builtin_bit_cast(u16, h); }
DEV float h2f(u16 h){ return (float)__builtin_bit_cast(_Float16, h); }

DEV f32x4 mfma16(f16x8 a, f16x8 b, f32x4 c){
  return __builtin_amdgcn_mfma_f32_16x16x32_f16(a, b, c, 0, 0, 0);
}

// relu(fp16_a + fp16_b) on a packed pair -> v_pk_add_f16 + v_pk_max_f16
DEV unsigned rap(unsigned a, unsigned b){
  f16x2 ha = __builtin_bit_cast(f16x2, a);
  f16x2 hb = __builtin_bit_cast(f16x2, b);
  f16x2 s = ha + hb;
  const _Float16 z = (_Float16)0;
  s.x = s.x > z ? s.x : z;
  s.y = s.y > z ? s.y : z;
  return __builtin_bit_cast(unsigned, s);
}

DEV f16x8 build_frag(uint4 s, uint4 r){
  uint4 o;
  o.x = rap(s.x, r.x); o.y = rap(s.y, r.y);
  o.z = rap(s.z, r.z); o.w = rap(s.w, r.w);
  return __builtin_bit_cast(f16x8, o);
}

// Sizes: B=64, N=64, F=64, H=256, O=64, T=4, E=4032
// ws layout (bytes):
//  FLAG  int       @ 0
//  W1T [4][256][128] fp16 @ 256
//  W2T [4][64][256]  fp16 @ 262400
//  OW1T [256][128]   fp16 @ 393472
//  OW2T [256][256]   fp16 @ 459008
//  OW3T [64][256]    fp16 @ 590080
//  B1 [4][256] @ 622848 | B2 [4][64] @ 624896 | OB1 @ 625408 | OB2 @ 625920 | OB3 @ 626432
//  Xc  [64][64][64]  fp16 @ 626688
//  RTc [64][4032][4] fp16 @ 1150976
//  S1  [4][64][64][256] fp16 @ 3215360
//  R1  [4][64][64][256] fp16 @ 11603968   (b1 folded in)
//  AGG [64][64][64] f32 @ 19992576
#define OFF_W1T  256
#define OFF_W2T  262400
#define OFF_OW1T 393472
#define OFF_OW2T 459008
#define OFF_OW3T 590080
#define OFF_B1   622848
#define OFF_B2   624896
#define OFF_OB1  625408
#define OFF_OB2  625920
#define OFF_OB3  626432
#define OFF_XC   626688
#define OFF_RTC  1150976
#define OFF_S1   3215360
#define OFF_R1   11603968
#define OFF_AGG  19992576

// ---------------- K-1: dtype sniff ----------------
// Even-indexed u16s of a bf16 buffer are sane bf16 values; of an fp32 buffer
// they are random mantissa bits (sane-exponent prob ~0.16). Ballot-count.
__global__ void k_sniff(const u16* __restrict__ x, int* __restrict__ flag){
  int l = threadIdx.x;
  u16 u = x[2 * l];                   // first 256 bytes — safe in both dtypes
  int e = (u >> 7) & 0xFF;
  int ok = (e >= 103 && e <= 143) ? 1 : 0;
  unsigned long long m = __ballot(ok);
  if(l == 0) *flag = (__builtin_popcountll(m) >= 40) ? 1 : 0;  // 1 = bf16 I/O
}

DEV float ldin(const void* p, int i, int isbf){
  return isbf ? bf2f(((const u16*)p)[i]) : ((const float*)p)[i];
}

// ---------------- K0: convert + transpose everything to canonical fp16 ----------------
__global__ __launch_bounds__(256) void k_cvt(const void* __restrict__ x, const void* __restrict__ rt,
    const void* __restrict__ w1, const void* __restrict__ b1,
    const void* __restrict__ w2, const void* __restrict__ b2,
    const void* __restrict__ ow1, const void* __restrict__ ob1,
    const void* __restrict__ ow2, const void* __restrict__ ob2,
    const void* __restrict__ ow3, const void* __restrict__ ob3,
    char* __restrict__ ws){
  const int isbf = *(const int*)ws;
  int n = blockIdx.x * 256 + threadIdx.x;
  if(n < 131072){ int t = n >> 15, r = n & 32767, h = r >> 7, k = r & 127;
    ((u16*)(ws+OFF_W1T))[n] = f2h(ldin(w1, t*32768 + k*256 + h, isbf)); return; }
  n -= 131072;
  if(n < 65536){ int t = n >> 14, r = n & 16383, o = r >> 8, k = r & 255;
    ((u16*)(ws+OFF_W2T))[n] = f2h(ldin(w2, t*16384 + k*64 + o, isbf)); return; }
  n -= 65536;
  if(n < 32768){ int h = n >> 7, k = n & 127;
    ((u16*)(ws+OFF_OW1T))[n] = f2h(ldin(ow1, k*256 + h, isbf)); return; }
  n -= 32768;
  if(n < 65536){ int h = n >> 8, k = n & 255;
    ((u16*)(ws+OFF_OW2T))[n] = f2h(ldin(ow2, k*256 + h, isbf)); return; }
  n -= 65536;
  if(n < 16384){ int o = n >> 8, k = n & 255;
    ((u16*)(ws+OFF_OW3T))[n] = f2h(ldin(ow3, k*64 + o, isbf)); return; }
  n -= 16384;
  if(n < 262144){ ((u16*)(ws+OFF_XC))[n] = f2h(ldin(x, n, isbf)); return; }
  n -= 262144;
  if(n < 1032192){ ((u16*)(ws+OFF_RTC))[n] = f2h(ldin(rt, n, isbf)); return; }
  n -= 1032192;
  if(n < 1024){ ((u16*)(ws+OFF_B1))[n] = f2h(ldin(b1, n, isbf)); return; }
  n -= 1024;
  if(n < 256){ ((u16*)(ws+OFF_B2))[n] = f2h(ldin(b2, n, isbf)); return; }
  n -= 256;
  if(n < 256){ ((u16*)(ws+OFF_OB1))[n] = f2h(ldin(ob1, n, isbf)); return; }
  n -= 256;
  if(n < 256){ ((u16*)(ws+OFF_OB2))[n] = f2h(ldin(ob2, n, isbf)); return; }
  n -= 256;
  if(n < 64){ ((u16*)(ws+OFF_OB3))[n] = f2h(ldin(ob3, n, isbf)); return; }
}

// ---------------- K1: S1/R1 = x @ w1-half (+b1 on receiver half) ----------------
__global__ __launch_bounds__(256) void k_s1r1(const u16* __restrict__ Xc, const u16* __restrict__ W1T,
    const u16* __restrict__ B1c, u16* __restrict__ S1, u16* __restrict__ R1){
  __shared__ __align__(16) u16 sX[64][72];
  __shared__ __align__(16) u16 sW[256][72];
  const int tid = threadIdx.x, bid = blockIdx.x;
  const int b = bid & 63, th = bid >> 6, t = th >> 1, half = th & 1;
  {
    const uint4* src = (const uint4*)(Xc + b*4096);
    #pragma unroll
    for(int it=0; it<2; ++it){
      int c = tid + it*256; int row = c >> 3, col = (c & 7) * 8;
      *(uint4*)&sX[row][col] = src[c];
    }
    const u16* base = W1T + t*32768 + half*64;
    #pragma unroll
    for(int it=0; it<8; ++it){
      int c = tid + it*256; int h = c >> 3, kc = (c & 7) * 8;
      *(uint4*)&sW[h][kc] = *(const uint4*)(base + h*128 + kc);
    }
  }
  __syncthreads();
  const int wv = tid >> 6, l = tid & 63, ml = l & 15, q = l >> 4;
  const f32x4 z = {0.f,0.f,0.f,0.f};
  f32x4 acc[4][4];
  #pragma unroll
  for(int mt=0;mt<4;++mt){ acc[mt][0]=z; acc[mt][1]=z; acc[mt][2]=z; acc[mt][3]=z; }
  #pragma unroll
  for(int ks=0; ks<2; ++ks){
    const int kb = ks*32 + q*8;
    f16x8 af[4], bff[4];
    #pragma unroll
    for(int mt=0;mt<4;++mt) af[mt] = *(const f16x8*)&sX[mt*16 + ml][kb];
    #pragma unroll
    for(int nt=0;nt<4;++nt) bff[nt] = *(const f16x8*)&sW[wv*64 + nt*16 + ml][kb];
    #pragma unroll
    for(int mt=0;mt<4;++mt)
      #pragma unroll
      for(int nt=0;nt<4;++nt)
        acc[mt][nt] = mfma16(af[mt], bff[nt], acc[mt][nt]);
  }
  u16* dst = (half ? R1 : S1) + (t*64 + b)*16384;
  #pragma unroll
  for(int nt=0;nt<4;++nt){
    const int h = wv*64 + nt*16 + ml;
    const float bias = half ? h2f(B1c[t*256 + h]) : 0.0f;
    #pragma unroll
    for(int mt=0;mt<4;++mt)
      #pragma unroll
      for(int r=0;r<4;++r){
        int irow = mt*16 + q*4 + r;
        dst[irow*256 + h] = f2h(acc[mt][nt][r] + bias);
      }
  }
}

// ---------------- K2: per-edge layer-2 + weighted receiver aggregation ----------------
// grid 512: block = (b, 8 consecutive receivers j). wave = edge type t.
__global__ __launch_bounds__(256, 2) void k_edge(const u16* __restrict__ RTc, const u16* __restrict__ W2T,
    const u16* __restrict__ B2c, const u16* __restrict__ S1, const u16* __restrict__ R1,
    float* __restrict__ AGG){
  __shared__ float sRT[4][64];
  __shared__ float sAgg[64];
  const int tid = threadIdx.x;
  const int t = tid >> 6, l = tid & 63, ml = l & 15, q = l >> 4;
  const int b = blockIdx.x >> 3, j0 = (blockIdx.x & 7) * 8;
  f16x8 bfr[4][8];                 // whole w2T[t] (64 o x 256 k) persistent: 128 VGPRs
  {
    const u16* w2t = W2T + t*16384;
    #pragma unroll
    for(int nt=0;nt<4;++nt)
      #pragma unroll
      for(int ks=0;ks<8;++ks)
        bfr[nt][ks] = *(const f16x8*)(w2t + (nt*16 + ml)*256 + ks*32 + q*8);
  }
  float bias2[4];
  #pragma unroll
  for(int nt=0;nt<4;++nt) bias2[nt] = h2f(B2c[t*64 + nt*16 + ml]);
  const u16* s1b = S1 + (t*64 + b)*16384;
  const u16* r1b = R1 + (t*64 + b)*16384;
  const f32x4 z = {0.f,0.f,0.f,0.f};
  for(int jj=0; jj<8; ++jj){
    const int j = j0 + jj;
    if(tid < 64) sAgg[tid] = 0.0f;
    {
      const int i = l;
      float v = 0.0f;
      if(i != j){
        int e = i*63 + j - (j > i ? 1 : 0);
        v = h2f(RTc[(b*4032 + e)*4 + t]);
      }
      sRT[t][i] = v;
    }
    __syncthreads();
    f32x4 acc[4][4];
    #pragma unroll
    for(int mt=0;mt<4;++mt){ acc[mt][0]=z; acc[mt][1]=z; acc[mt][2]=z; acc[mt][3]=z; }
    const u16* r1j = r1b + j*256;
    #pragma unroll
    for(int ks=0;ks<8;++ks){
      const int kb = ks*32 + q*8;
      uint4 ru = *(const uint4*)(r1j + kb);
      #pragma unroll
      for(int mt=0;mt<4;++mt){
        uint4 su = *(const uint4*)(s1b + (mt*16 + ml)*256 + kb);
        f16x8 af = build_frag(su, ru);       // relu(S1+R1) in-register
        #pragma unroll
        for(int nt=0;nt<4;++nt) acc[mt][nt] = mfma16(af, bfr[nt][ks], acc[mt][nt]);
      }
    }
    // epilogue: m2 = relu(C + b2); weighted col-sum over sender rows i
    float cs[4] = {0.f,0.f,0.f,0.f};
    #pragma unroll
    for(int mt=0;mt<4;++mt){
      float rw[4];
      #pragma unroll
      for(int r=0;r<4;++r) rw[r] = sRT[t][mt*16 + q*4 + r];
      #pragma unroll
      for(int nt=0;nt<4;++nt)
        #pragma unroll
        for(int r=0;r<4;++r){
          float v = fmaxf(acc[mt][nt][r] + bias2[nt], 0.0f);
          cs[nt] += v * rw[r];
        }
    }
    #pragma unroll
    for(int nt=0;nt<4;++nt){
      float v = cs[nt];
      v += __shfl_xor(v, 16, 64);
      v += __shfl_xor(v, 32, 64);
      if(q == 0) atomicAdd(&sAgg[nt*16 + ml], v);   // combine 4 type-waves
    }
    __syncthreads();
    if(tid < 64) AGG[(b*64 + j)*64 + tid] = sAgg[tid];
    __syncthreads();
  }
}

// ---------------- K3: node MLP (aug=[x,agg] -> 256 -> 256 -> 64) ----------------
__global__ __launch_bounds__(256) void k_node(const u16* __restrict__ Xc, const float* __restrict__ AGG,
    const u16* __restrict__ OW1T, const u16* __restrict__ OB1c,
    const u16* __restrict__ OW2T, const u16* __restrict__ OB2c,
    const u16* __restrict__ OW3T, const u16* __restrict__ OB3c,
    void* __restrict__ out, const int* __restrict__ flag){
  __shared__ __align__(16) u16 sA[64][136];
  __shared__ __align__(16) u16 sH[64][264];
  __shared__ __align__(16) u16 sH2[64][264];
  __shared__ __align__(16) u16 sW[64][264];
  const int tid = threadIdx.x, bb = blockIdx.x;
  const int isbf = *flag;
  {
    const uint4* src = (const uint4*)(Xc + bb*4096);
    #pragma unroll
    for(int it=0; it<2; ++it){
      int c = tid + it*256; int row = c >> 3, col = (c & 7)*8;
      *(uint4*)&sA[row][col] = src[c];
    }
    const float* ag = AGG + bb*4096;
    #pragma unroll
    for(int it=0; it<16; ++it){
      int c = tid + it*256; int row = c >> 6, col = c & 63;
      sA[row][64 + col] = f2h(ag[c]);
    }
  }
  const int wv = tid >> 6, l = tid & 63, ml = l & 15, q = l >> 4;
  const f32x4 z = {0.f,0.f,0.f,0.f};
  __syncthreads();
  // L1: K=128 from sA -> sH (256 cols in 4 chunks of 64)
  for(int nc=0; nc<4; ++nc){
    #pragma unroll
    for(int it=0; it<4; ++it){
      int c = tid + it*256; int h = c >> 4, kc = (c & 15)*8;
      *(uint4*)&sW[h][kc] = *(const uint4*)(OW1T + (nc*64 + h)*128 + kc);
    }
    __syncthreads();
    f32x4 acc[4] = {z,z,z,z};
    #pragma unroll
    for(int ks=0; ks<4; ++ks){
      int kb = ks*32 + q*8;
      f16x8 bfrag = *(const f16x8*)&sW[wv*16 + ml][kb];
      #pragma unroll
      for(int mt=0;mt<4;++mt){
        f16x8 afrag = *(const f16x8*)&sA[mt*16 + ml][kb];
        acc[mt] = mfma16(afrag, bfrag, acc[mt]);
      }
    }
    const int h = nc*64 + wv*16 + ml;
    const float bias = h2f(OB1c[h]);
    #pragma unroll
    for(int mt=0;mt<4;++mt)
      #pragma unroll
      for(int r=0;r<4;++r){
        int row = mt*16 + q*4 + r;
        sH[row][h] = f2h(fmaxf(acc[mt][r] + bias, 0.0f));
      }
    __syncthreads();
  }
  // L2: K=256 from sH -> sH2
  for(int nc=0; nc<4; ++nc){
    #pragma unroll
    for(int it=0; it<8; ++it){
      int c = tid + it*256; int h = c >> 5, kc = (c & 31)*8;
      *(uint4*)&sW[h][kc] = *(const uint4*)(OW2T + (nc*64 + h)*256 + kc);
    }
    __syncthreads();
    f32x4 acc[4] = {z,z,z,z};
    #pragma unroll
    for(int ks=0; ks<8; ++ks){
      int kb = ks*32 + q*8;
      f16x8 bfrag = *(const f16x8*)&sW[wv*16 + ml][kb];
      #pragma unroll
      for(int mt=0;mt<4;++mt){
        f16x8 afrag = *(const f16x8*)&sH[mt*16 + ml][kb];
        acc[mt] = mfma16(afrag, bfrag, acc[mt]);
      }
    }
    const int h = nc*64 + wv*16 + ml;
    const float bias = h2f(OB2c[h]);
    #pragma unroll
    for(int mt=0;mt<4;++mt)
      #pragma unroll
      for(int r=0;r<4;++r){
        int row = mt*16 + q*4 + r;
        sH2[row][h] = f2h(fmaxf(acc[mt][r] + bias, 0.0f));
      }
    __syncthreads();
  }
  // L3: K=256 from sH2 -> out (no relu)
  {
    #pragma unroll
    for(int it=0; it<8; ++it){
      int c = tid + it*256; int h = c >> 5, kc = (c & 31)*8;
      *(uint4*)&sW[h][kc] = *(const uint4*)(OW3T + h*256 + kc);
    }
    __syncthreads();
    f32x4 acc[4] = {z,z,z,z};
    #pragma unroll
    for(int ks=0; ks<8; ++ks){
      int kb = ks*32 + q*8;
      f16x8 bfrag = *(const f16x8*)&sW[wv*16 + ml][kb];
      #pragma unroll
      for(int mt=0;mt<4;++mt){
        f16x8 afrag = *(const f16x8*)&sH2[mt*16 + ml][kb];
        acc[mt] = mfma16(afrag, bfrag, acc[mt]);
      }
    }
    const int o = wv*16 + ml;
    const float bias = h2f(OB3c[o]);
    #pragma unroll
    for(int mt=0;mt<4;++mt)
      #pragma unroll
      for(int r=0;r<4;++r){
        int row = mt*16 + q*4 + r;
        float v = acc[mt][r] + bias;
        int idx = bb*4096 + row*64 + o;
        if(isbf) ((u16*)out)[idx] = f2bf(v);
        else     ((float*)out)[idx] = v;
      }
  }
}

extern "C" void kernel_launch(void* const* d_in, const int* in_sizes, int n_in,
                              void* d_out, int out_size, void* d_ws, size_t ws_size,
                              hipStream_t stream){
  (void)in_sizes; (void)n_in; (void)out_size; (void)ws_size;
  char* ws = (char*)d_ws;
  u16* W1T  = (u16*)(ws + OFF_W1T);
  u16* W2T  = (u16*)(ws + OFF_W2T);
  u16* OW1T = (u16*)(ws + OFF_OW1T);
  u16* OW2T = (u16*)(ws + OFF_OW2T);
  u16* OW3T = (u16*)(ws + OFF_OW3T);
  u16* B1c  = (u16*)(ws + OFF_B1);
  u16* B2c  = (u16*)(ws + OFF_B2);
  u16* OB1c = (u16*)(ws + OFF_OB1);
  u16* OB2c = (u16*)(ws + OFF_OB2);
  u16* OB3c = (u16*)(ws + OFF_OB3);
  u16* Xc   = (u16*)(ws + OFF_XC);
  u16* RTc  = (u16*)(ws + OFF_RTC);
  u16* S1   = (u16*)(ws + OFF_S1);
  u16* R1   = (u16*)(ws + OFF_R1);
  float* AGG = (float*)(ws + OFF_AGG);

  k_sniff<<<1, 64, 0, stream>>>((const u16*)d_in[0], (int*)ws);
  k_cvt<<<6280, 256, 0, stream>>>(d_in[0], d_in[1], d_in[4], d_in[5], d_in[6], d_in[7],
                                  d_in[8], d_in[9], d_in[10], d_in[11], d_in[12], d_in[13], ws);
  k_s1r1<<<512, 256, 0, stream>>>(Xc, W1T, B1c, S1, R1);
  k_edge<<<512, 256, 0, stream>>>(RTc, W2T, B2c, S1, R1, AGG);
  k_node<<<64, 256, 0, stream>>>(Xc, AGG, OW1T, OB1c, OW2T, OB2c, OW3T, OB3c, d_out, (const int*)ws);
}

// Round 4
// 170.746 us; speedup vs baseline: 1.4776x; 1.4776x over previous
//
#include <hip/hip_runtime.h>

typedef unsigned short u16;
typedef __attribute__((ext_vector_type(8))) _Float16 f16x8;
typedef __attribute__((ext_vector_type(2))) _Float16 f16x2;
typedef __attribute__((ext_vector_type(4))) float f32x4;

#define DEV static __device__ __forceinline__

DEV float bf2f(u16 h){ unsigned u = ((unsigned)h) << 16; return __builtin_bit_cast(float, u); }
DEV u16 f2bf(float f){ unsigned u = __builtin_bit_cast(unsigned, f); u += 0x7FFFu + ((u >> 16) & 1u); return (u16)(u >> 16); }
DEV u16 f2h(float f){ _Float16 h = (_Float16)f; return __builtin_bit_cast(u16, h); }
DEV float h2f(u16 h){ return (float)__builtin_bit_cast(_Float16, h); }

DEV f32x4 mfma16(f16x8 a, f16x8 b, f32x4 c){
  return __builtin_amdgcn_mfma_f32_16x16x32_f16(a, b, c, 0, 0, 0);
}

// relu(fp16_a + fp16_b) on a packed pair -> v_pk_add_f16 + v_pk_max_f16
DEV unsigned rap(unsigned a, unsigned b){
  f16x2 ha = __builtin_bit_cast(f16x2, a);
  f16x2 hb = __builtin_bit_cast(f16x2, b);
  f16x2 s = ha + hb;
  const _Float16 z = (_Float16)0;
  s.x = s.x > z ? s.x : z;
  s.y = s.y > z ? s.y : z;
  return __builtin_bit_cast(unsigned, s);
}

DEV f16x8 build_frag(uint4 s, uint4 r){
  uint4 o;
  o.x = rap(s.x, r.x); o.y = rap(s.y, r.y);
  o.z = rap(s.z, r.z); o.w = rap(s.w, r.w);
  return __builtin_bit_cast(f16x8, o);
}

// Sizes: B=64, N=64, F=64, H=256, O=64, T=4, E=4032
// ws layout (bytes): FLAG@0 | W1T@256 | W2T@262400 | OW1T@393472 | OW2T@459008
//  | OW3T@590080 | B1@622848 | B2@624896 | OB1@625408 | OB2@625920 | OB3@626432
//  | Xc@626688 | RTc@1150976 | S1@3215360 | R1@11603968 | AGG(f32)@19992576
#define OFF_W1T  256
#define OFF_W2T  262400
#define OFF_OW1T 393472
#define OFF_OW2T 459008
#define OFF_OW3T 590080
#define OFF_B1   622848
#define OFF_B2   624896
#define OFF_OB1  625408
#define OFF_OB2  625920
#define OFF_OB3  626432
#define OFF_XC   626688
#define OFF_RTC  1150976
#define OFF_S1   3215360
#define OFF_R1   11603968
#define OFF_AGG  19992576

// ---------------- K-1: dtype sniff ----------------
__global__ void k_sniff(const u16* __restrict__ x, int* __restrict__ flag){
  int l = threadIdx.x;
  u16 u = x[2 * l];
  int e = (u >> 7) & 0xFF;
  int ok = (e >= 103 && e <= 143) ? 1 : 0;
  unsigned long long m = __ballot(ok);
  if(l == 0) *flag = (__builtin_popcountll(m) >= 40) ? 1 : 0;  // 1 = bf16 I/O
}

DEV float ldin(const void* p, int i, int isbf){
  return isbf ? bf2f(((const u16*)p)[i]) : ((const float*)p)[i];
}

// ---------------- K0a: tiled transpose+convert for the 5 weight matrices ----------------
// src [G][R][C] -> dst [G][C][R], 32x32 LDS tiles, coalesced read+write.
__global__ __launch_bounds__(256) void k_tr(const void* __restrict__ w1, const void* __restrict__ w2,
    const void* __restrict__ ow1, const void* __restrict__ ow2, const void* __restrict__ ow3,
    char* __restrict__ ws){
  const int isbf = *(const int*)ws;
  __shared__ float tile[32][33];
  int bid = blockIdx.x, tid = threadIdx.x;
  const void* src; u16* dst; int R, C, off, r0, c0;
  if(bid < 128){ int g = bid >> 5, tt = bid & 31;
    src = w1; dst = (u16*)(ws + OFF_W1T); R = 128; C = 256; off = g * 32768;
    r0 = (tt >> 3) << 5; c0 = (tt & 7) << 5;
  } else if(bid < 192){ int bb = bid - 128; int g = bb >> 4, tt = bb & 15;
    src = w2; dst = (u16*)(ws + OFF_W2T); R = 256; C = 64; off = g * 16384;
    r0 = (tt >> 1) << 5; c0 = (tt & 1) << 5;
  } else if(bid < 224){ int bb = bid - 192;
    src = ow1; dst = (u16*)(ws + OFF_OW1T); R = 128; C = 256; off = 0;
    r0 = (bb >> 3) << 5; c0 = (bb & 7) << 5;
  } else if(bid < 288){ int bb = bid - 224;
    src = ow2; dst = (u16*)(ws + OFF_OW2T); R = 256; C = 256; off = 0;
    r0 = (bb >> 3) << 5; c0 = (bb & 7) << 5;
  } else { int bb = bid - 288;
    src = ow3; dst = (u16*)(ws + OFF_OW3T); R = 256; C = 64; off = 0;
    r0 = (bb >> 1) << 5; c0 = (bb & 1) << 5;
  }
  int tx = tid & 31, ty = tid >> 5;
  #pragma unroll
  for(int p = 0; p < 4; ++p){
    int r = ty + p * 8;
    tile[r][tx] = ldin(src, off + (r0 + r) * C + c0 + tx, isbf);
  }
  __syncthreads();
  #pragma unroll
  for(int p = 0; p < 4; ++p){
    int c = ty + p * 8;
    dst[off + (c0 + c) * R + r0 + tx] = f2h(tile[tx][c]);
  }
}

// ---------------- K0b: coalesced elementwise converts (x, rel_type, biases) ----------------
__global__ __launch_bounds__(256) void k_cvt2(const void* __restrict__ x, const void* __restrict__ rt,
    const void* __restrict__ b1, const void* __restrict__ b2,
    const void* __restrict__ ob1, const void* __restrict__ ob2, const void* __restrict__ ob3,
    char* __restrict__ ws){
  const int isbf = *(const int*)ws;
  int n = blockIdx.x * 256 + threadIdx.x;
  if(n < 262144){ ((u16*)(ws+OFF_XC))[n] = f2h(ldin(x, n, isbf)); return; }
  n -= 262144;
  if(n < 1032192){ ((u16*)(ws+OFF_RTC))[n] = f2h(ldin(rt, n, isbf)); return; }
  n -= 1032192;
  if(n < 1024){ ((u16*)(ws+OFF_B1))[n] = f2h(ldin(b1, n, isbf)); return; }
  n -= 1024;
  if(n < 256){ ((u16*)(ws+OFF_B2))[n] = f2h(ldin(b2, n, isbf)); return; }
  n -= 256;
  if(n < 256){ ((u16*)(ws+OFF_OB1))[n] = f2h(ldin(ob1, n, isbf)); return; }
  n -= 256;
  if(n < 256){ ((u16*)(ws+OFF_OB2))[n] = f2h(ldin(ob2, n, isbf)); return; }
  n -= 256;
  if(n < 64){ ((u16*)(ws+OFF_OB3))[n] = f2h(ldin(ob3, n, isbf)); return; }
}

// ---------------- K1: S1/R1 = x @ w1-half (+b1 on receiver half) ----------------
__global__ __launch_bounds__(256) void k_s1r1(const u16* __restrict__ Xc, const u16* __restrict__ W1T,
    const u16* __restrict__ B1c, u16* __restrict__ S1, u16* __restrict__ R1){
  __shared__ __align__(16) u16 sX[64][72];
  __shared__ __align__(16) u16 sW[256][72];
  const int tid = threadIdx.x, bid = blockIdx.x;
  const int b = bid & 63, th = bid >> 6, t = th >> 1, half = th & 1;
  {
    const uint4* src = (const uint4*)(Xc + b*4096);
    #pragma unroll
    for(int it=0; it<2; ++it){
      int c = tid + it*256; int row = c >> 3, col = (c & 7) * 8;
      *(uint4*)&sX[row][col] = src[c];
    }
    const u16* base = W1T + t*32768 + half*64;
    #pragma unroll
    for(int it=0; it<8; ++it){
      int c = tid + it*256; int h = c >> 3, kc = (c & 7) * 8;
      *(uint4*)&sW[h][kc] = *(const uint4*)(base + h*128 + kc);
    }
  }
  __syncthreads();
  const int wv = tid >> 6, l = tid & 63, ml = l & 15, q = l >> 4;
  const f32x4 z = {0.f,0.f,0.f,0.f};
  f32x4 acc[4][4];
  #pragma unroll
  for(int mt=0;mt<4;++mt){ acc[mt][0]=z; acc[mt][1]=z; acc[mt][2]=z; acc[mt][3]=z; }
  #pragma unroll
  for(int ks=0; ks<2; ++ks){
    const int kb = ks*32 + q*8;
    f16x8 af[4], bff[4];
    #pragma unroll
    for(int mt=0;mt<4;++mt) af[mt] = *(const f16x8*)&sX[mt*16 + ml][kb];
    #pragma unroll
    for(int nt=0;nt<4;++nt) bff[nt] = *(const f16x8*)&sW[wv*64 + nt*16 + ml][kb];
    #pragma unroll
    for(int mt=0;mt<4;++mt)
      #pragma unroll
      for(int nt=0;nt<4;++nt)
        acc[mt][nt] = mfma16(af[mt], bff[nt], acc[mt][nt]);
  }
  u16* dst = (half ? R1 : S1) + (t*64 + b)*16384;
  #pragma unroll
  for(int nt=0;nt<4;++nt){
    const int h = wv*64 + nt*16 + ml;
    const float bias = half ? h2f(B1c[t*256 + h]) : 0.0f;
    #pragma unroll
    for(int mt=0;mt<4;++mt)
      #pragma unroll
      for(int r=0;r<4;++r){
        int irow = mt*16 + q*4 + r;
        dst[irow*256 + h] = f2h(acc[mt][nt][r] + bias);
      }
  }
}

// ---------------- K2: per-edge layer-2 + weighted receiver aggregation ----------------
// grid 256 (= CU count): block = (b, group of 16 receivers j). wave = edge type t.
// S1 fragments (su) AND w2 fragments (bfr) register-resident; only R1 row streams per j.
// No barriers in the j loop: per-wave LDS rel_type prefetch + LDS-atomic combine.
__global__ __launch_bounds__(256, 1) void k_edge(const u16* __restrict__ RTc, const u16* __restrict__ W2T,
    const u16* __restrict__ B2c, const u16* __restrict__ S1, const u16* __restrict__ R1,
    float* __restrict__ AGG){
  __shared__ float sRTa[4][16][64];
  __shared__ float sAggB[1024];
  const int tid = threadIdx.x;
  const int t = tid >> 6, l = tid & 63, ml = l & 15, q = l >> 4;
  const int b = blockIdx.x >> 2, j0 = (blockIdx.x & 3) * 16;
  #pragma unroll
  for(int it=0; it<4; ++it) sAggB[it*256 + tid] = 0.0f;
  // prefetch this block's 16 receivers' rel_type weights (per-wave, same-wave use)
  #pragma unroll 1
  for(int jj=0; jj<16; ++jj){
    int j = j0 + jj, i = l;
    float v = 0.0f;
    if(i != j){ int e = i*63 + j - (j > i ? 1 : 0); v = h2f(RTc[(b*4032 + e)*4 + t]); }
    sRTa[t][jj][i] = v;
  }
  __syncthreads();          // covers sAggB zero-init
  f16x8 bfr[4][8];          // whole w2T[t]: 128 VGPRs
  {
    const u16* w2t = W2T + t*16384;
    #pragma unroll
    for(int nt=0;nt<4;++nt)
      #pragma unroll
      for(int ks=0;ks<8;++ks)
        bfr[nt][ks] = *(const f16x8*)(w2t + (nt*16 + ml)*256 + ks*32 + q*8);
  }
  uint4 su[4][8];           // whole S1[t][b] A-side: 128 VGPRs, loaded ONCE
  const u16* s1b = S1 + (t*64 + b)*16384;
  #pragma unroll
  for(int mt=0;mt<4;++mt)
    #pragma unroll
    for(int ks=0;ks<8;++ks)
      su[mt][ks] = *(const uint4*)(s1b + (mt*16 + ml)*256 + ks*32 + q*8);
  float bias2[4];
  #pragma unroll
  for(int nt=0;nt<4;++nt) bias2[nt] = h2f(B2c[t*64 + nt*16 + ml]);
  const u16* r1b = R1 + (t*64 + b)*16384;
  const f32x4 z = {0.f,0.f,0.f,0.f};
  uint4 ru[8], run[8];
  #pragma unroll
  for(int ks=0;ks<8;++ks) ru[ks] = *(const uint4*)(r1b + j0*256 + ks*32 + q*8);
  #pragma unroll 1
  for(int jj=0; jj<16; ++jj){
    if(jj < 15){            // prefetch next receiver row while MFMAs run
      const u16* r1n = r1b + (j0 + jj + 1)*256;
      #pragma unroll
      for(int ks=0;ks<8;++ks) run[ks] = *(const uint4*)(r1n + ks*32 + q*8);
    }
    f32x4 acc[4][4];
    #pragma unroll
    for(int mt=0;mt<4;++mt){ acc[mt][0]=z; acc[mt][1]=z; acc[mt][2]=z; acc[mt][3]=z; }
    #pragma unroll
    for(int ks=0;ks<8;++ks){
      #pragma unroll
      for(int mt=0;mt<4;++mt){
        f16x8 af = build_frag(su[mt][ks], ru[ks]);   // relu(S1+R1) in-register
        #pragma unroll
        for(int nt=0;nt<4;++nt) acc[mt][nt] = mfma16(af, bfr[nt][ks], acc[mt][nt]);
      }
    }
    // epilogue: relu(C + b2), weighted column-sum over sender rows i
    float cs[4] = {0.f,0.f,0.f,0.f};
    #pragma unroll
    for(int mt=0;mt<4;++mt){
      float rw[4];
      #pragma unroll
      for(int r=0;r<4;++r) rw[r] = sRTa[t][jj][mt*16 + q*4 + r];
      #pragma unroll
      for(int nt=0;nt<4;++nt)
        #pragma unroll
        for(int r=0;r<4;++r)
          cs[nt] += fmaxf(acc[mt][nt][r] + bias2[nt], 0.0f) * rw[r];
    }
    #pragma unroll
    for(int nt=0;nt<4;++nt){
      float v = cs[nt];
      v += __shfl_xor(v, 16, 64);
      v += __shfl_xor(v, 32, 64);
      if(q == 0) atomicAdd(&sAggB[jj*64 + nt*16 + ml], v);   // combine 4 type-waves
    }
    #pragma unroll
    for(int ks=0;ks<8;++ks) ru[ks] = run[ks];
  }
  __syncthreads();
  float* aggb = AGG + (b*64 + j0)*64;
  #pragma unroll
  for(int it=0; it<4; ++it) aggb[it*256 + tid] = sAggB[it*256 + tid];
}

// ---------------- K3: node MLP (aug=[x,agg] -> 256 -> 256 -> 64) ----------------
__global__ __launch_bounds__(256) void k_node(const u16* __restrict__ Xc, const float* __restrict__ AGG,
    const u16* __restrict__ OW1T, const u16* __restrict__ OB1c,
    const u16* __restrict__ OW2T, const u16* __restrict__ OB2c,
    const u16* __restrict__ OW3T, const u16* __restrict__ OB3c,
    void* __restrict__ out, const int* __restrict__ flag){
  __shared__ __align__(16) u16 sA[64][136];
  __shared__ __align__(16) u16 sH[64][264];
  __shared__ __align__(16) u16 sH2[64][264];
  __shared__ __align__(16) u16 sW[64][264];
  const int tid = threadIdx.x, bb = blockIdx.x;
  const int isbf = *flag;
  {
    const uint4* src = (const uint4*)(Xc + bb*4096);
    #pragma unroll
    for(int it=0; it<2; ++it){
      int c = tid + it*256; int row = c >> 3, col = (c & 7)*8;
      *(uint4*)&sA[row][col] = src[c];
    }
    const float* ag = AGG + bb*4096;
    #pragma unroll
    for(int it=0; it<16; ++it){
      int c = tid + it*256; int row = c >> 6, col = c & 63;
      sA[row][64 + col] = f2h(ag[c]);
    }
  }
  const int wv = tid >> 6, l = tid & 63, ml = l & 15, q = l >> 4;
  const f32x4 z = {0.f,0.f,0.f,0.f};
  __syncthreads();
  for(int nc=0; nc<4; ++nc){
    #pragma unroll
    for(int it=0; it<4; ++it){
      int c = tid + it*256; int h = c >> 4, kc = (c & 15)*8;
      *(uint4*)&sW[h][kc] = *(const uint4*)(OW1T + (nc*64 + h)*128 + kc);
    }
    __syncthreads();
    f32x4 acc[4] = {z,z,z,z};
    #pragma unroll
    for(int ks=0; ks<4; ++ks){
      int kb = ks*32 + q*8;
      f16x8 bfrag = *(const f16x8*)&sW[wv*16 + ml][kb];
      #pragma unroll
      for(int mt=0;mt<4;++mt){
        f16x8 afrag = *(const f16x8*)&sA[mt*16 + ml][kb];
        acc[mt] = mfma16(afrag, bfrag, acc[mt]);
      }
    }
    const int h = nc*64 + wv*16 + ml;
    const float bias = h2f(OB1c[h]);
    #pragma unroll
    for(int mt=0;mt<4;++mt)
      #pragma unroll
      for(int r=0;r<4;++r){
        int row = mt*16 + q*4 + r;
        sH[row][h] = f2h(fmaxf(acc[mt][r] + bias, 0.0f));
      }
    __syncthreads();
  }
  for(int nc=0; nc<4; ++nc){
    #pragma unroll
    for(int it=0; it<8; ++it){
      int c = tid + it*256; int h = c >> 5, kc = (c & 31)*8;
      *(uint4*)&sW[h][kc] = *(const uint4*)(OW2T + (nc*64 + h)*256 + kc);
    }
    __syncthreads();
    f32x4 acc[4] = {z,z,z,z};
    #pragma unroll
    for(int ks=0; ks<8; ++ks){
      int kb = ks*32 + q*8;
      f16x8 bfrag = *(const f16x8*)&sW[wv*16 + ml][kb];
      #pragma unroll
      for(int mt=0;mt<4;++mt){
        f16x8 afrag = *(const f16x8*)&sH[mt*16 + ml][kb];
        acc[mt] = mfma16(afrag, bfrag, acc[mt]);
      }
    }
    const int h = nc*64 + wv*16 + ml;
    const float bias = h2f(OB2c[h]);
    #pragma unroll
    for(int mt=0;mt<4;++mt)
      #pragma unroll
      for(int r=0;r<4;++r){
        int row = mt*16 + q*4 + r;
        sH2[row][h] = f2h(fmaxf(acc[mt][r] + bias, 0.0f));
      }
    __syncthreads();
  }
  {
    #pragma unroll
    for(int it=0; it<8; ++it){
      int c = tid + it*256; int h = c >> 5, kc = (c & 31)*8;
      *(uint4*)&sW[h][kc] = *(const uint4*)(OW3T + h*256 + kc);
    }
    __syncthreads();
    f32x4 acc[4] = {z,z,z,z};
    #pragma unroll
    for(int ks=0; ks<8; ++ks){
      int kb = ks*32 + q*8;
      f16x8 bfrag = *(const f16x8*)&sW[wv*16 + ml][kb];
      #pragma unroll
      for(int mt=0;mt<4;++mt){
        f16x8 afrag = *(const f16x8*)&sH2[mt*16 + ml][kb];
        acc[mt] = mfma16(afrag, bfrag, acc[mt]);
      }
    }
    const int o = wv*16 + ml;
    const float bias = h2f(OB3c[o]);
    #pragma unroll
    for(int mt=0;mt<4;++mt)
      #pragma unroll
      for(int r=0;r<4;++r){
        int row = mt*16 + q*4 + r;
        float v = acc[mt][r] + bias;
        int idx = bb*4096 + row*64 + o;
        if(isbf) ((u16*)out)[idx] = f2bf(v);
        else     ((float*)out)[idx] = v;
      }
  }
}

extern "C" void kernel_launch(void* const* d_in, const int* in_sizes, int n_in,
                              void* d_out, int out_size, void* d_ws, size_t ws_size,
                              hipStream_t stream){
  (void)in_sizes; (void)n_in; (void)out_size; (void)ws_size;
  char* ws = (char*)d_ws;
  u16* W1T  = (u16*)(ws + OFF_W1T);
  u16* W2T  = (u16*)(ws + OFF_W2T);
  u16* OW1T = (u16*)(ws + OFF_OW1T);
  u16* OW2T = (u16*)(ws + OFF_OW2T);
  u16* OW3T = (u16*)(ws + OFF_OW3T);
  u16* B1c  = (u16*)(ws + OFF_B1);
  u16* B2c  = (u16*)(ws + OFF_B2);
  u16* OB1c = (u16*)(ws + OFF_OB1);
  u16* OB2c = (u16*)(ws + OFF_OB2);
  u16* OB3c = (u16*)(ws + OFF_OB3);
  u16* Xc   = (u16*)(ws + OFF_XC);
  u16* RTc  = (u16*)(ws + OFF_RTC);
  u16* S1   = (u16*)(ws + OFF_S1);
  u16* R1   = (u16*)(ws + OFF_R1);
  float* AGG = (float*)(ws + OFF_AGG);

  k_sniff<<<1, 64, 0, stream>>>((const u16*)d_in[0], (int*)ws);
  k_tr<<<304, 256, 0, stream>>>(d_in[4], d_in[6], d_in[8], d_in[10], d_in[12], ws);
  k_cvt2<<<5064, 256, 0, stream>>>(d_in[0], d_in[1], d_in[5], d_in[7],
                                   d_in[9], d_in[11], d_in[13], ws);
  k_s1r1<<<512, 256, 0, stream>>>(Xc, W1T, B1c, S1, R1);
  k_edge<<<256, 256, 0, stream>>>(RTc, W2T, B2c, S1, R1, AGG);
  k_node<<<64, 256, 0, stream>>>(Xc, AGG, OW1T, OB1c, OW2T, OB2c, OW3T, OB3c, d_out, (const int*)ws);
}